// Round 10
// baseline (3682.241 us; speedup 1.0000x reference)
//
#include <hip/hip_runtime.h>

// DenseDilatedKnnGraph: B=4, C=64, N=4096, K=9, DILATION=2 (k_eff=18)
// Input  d_in[0]: float32 (B, C, N, 1)  -> x[b][c][n] at ((b*64)+c)*4096 + n
// Output d_out:   int32   (2, B, N, 9)  -> [0]=neighbor idx (ranks 0,2,..,16), [1]=center n
//
// Grading ref is a numpy fp32 recompute ("ref=np"); we match it BIT-EXACTLY:
//  - einsum dot: sequential c-ascending fp32 accumulate, SEPARATE mul/add
//    roundings (no FMA) -> #pragma clang fp contract(off)
//  - x_square: numpy pairwise-sum AVX512 tree for n=64
//  - key = fl(fl(sq_n + fl(-2*d)) + sq_m); ties -> lower index
//
// Round-10. Two mechanisms identified from r2-r9 counters:
//  (1) occupancy law: waves/SIMD ~ floor(256/VGPR) regardless of
//      launch_bounds (28->8w, 48-60->4-5w, 88->2w). QB=4/MPT=16 (88 VGPR)
//      is unfixable; register state must shrink.
//  (2) s_load q-prefetch serializes: SMEM is unordered -> every use drains
//      lgkmcnt(0) including the just-issued prefetch -> full K$ latency per
//      c-step (r8: fewer instrs + same occ as r4, yet 340us slower).
// Fix: q via v_readlane (lane l of a broadcast VGPR holds q(c=l); per c one
// VALU op, no memory). QB=2, MPT=8, NT=512: acc 16 + xv 8 + qv 2 ->
// ~45 VGPR -> 5-6 waves/SIMD. In-loop dwordx4 loads, tournament selection.

#pragma clang fp contract(off)

#define BB    4
#define CDIM  64
#define NPTS  4096
#define KSEL  17   // need sorted positions 0..16 (every 2nd of top-18)
#define KOUT  9
#define QB    2
#define MPT   8    // m-values per thread
#define NT    512  // threads per block (8 waves)

__device__ __forceinline__ float rdlane(float v, int l) {
    return __uint_as_float(__builtin_amdgcn_readlane(__float_as_uint(v), l));
}

__global__ __launch_bounds__(256) void knn_sq(const float* __restrict__ x,
                                              float* __restrict__ sq) {
#pragma clang fp contract(off)
    int g = blockIdx.x * 256 + threadIdx.x;       // g = b*NPTS + m
    int b = g >> 12;
    int m = g & (NPTS - 1);
    const float* xb = x + (size_t)b * CDIM * NPTS + m;

    float a[CDIM];
    #pragma unroll
    for (int c = 0; c < CDIM; ++c) {
        float v = xb[c * NPTS];
        a[c] = v * v;
    }
    // numpy pairwise_sum, AVX512 (16-lane) path for n=64:
    float s16[16];
    #pragma unroll
    for (int i = 0; i < 16; ++i)
        s16[i] = (a[i] + a[i + 16]) + (a[i + 32] + a[i + 48]);
    float t8[8];
    #pragma unroll
    for (int i = 0; i < 8; ++i) t8[i] = s16[i] + s16[i + 8];
    float t4[4];
    #pragma unroll
    for (int i = 0; i < 4; ++i) t4[i] = t8[i] + t8[i + 4];
    float u0 = t4[0] + t4[2];
    float u1 = t4[1] + t4[3];
    sq[g] = u0 + u1;
}

__global__ __launch_bounds__(NT) void knn_main(const float* __restrict__ x,
                                               const float* __restrict__ sq,
                                               int* __restrict__ out) {
#pragma clang fp contract(off)
    const int blk = blockIdx.x;                   // 2048 blocks per b
    const int b   = blk >> 11;
    const int n0  = (blk & 2047) * QB;
    const int t   = threadIdx.x;

    __shared__ float wbK[QB][2][NT / 64];         // [query][parity][wave]
    __shared__ int   wbI[QB][2][NT / 64];

    const float* xb  = x + (size_t)b * CDIM * NPTS;
    const float* sqb = sq + (b << 12);
    const float* xp  = xb + MPT * t;              // this thread's m-range

    // q into VGPR broadcast: lane l holds q(c=l). One gather per query,
    // then per-c access is a single v_readlane (no memory, no latency).
    const int lane = t & 63;
    float qv0 = xb[(size_t)lane * NPTS + n0];
    float qv1 = xb[(size_t)lane * NPTS + n0 + 1];

    float acc0[MPT], acc1[MPT];

    // ---- fp32 dots, c ascending, separate mul/add roundings ----
    {   // c = 0: init acc = fl(q*x)
        const float4* xr = (const float4*)(xp);
        float4 v0 = xr[0], v1 = xr[1];
        const float xv[MPT] = {v0.x,v0.y,v0.z,v0.w, v1.x,v1.y,v1.z,v1.w};
        float qc0 = rdlane(qv0, 0), qc1 = rdlane(qv1, 0);
        #pragma unroll
        for (int j = 0; j < MPT; ++j) {
            acc0[j] = qc0 * xv[j];
            acc1[j] = qc1 * xv[j];
        }
    }
    #pragma unroll 4
    for (int c = 1; c < CDIM; ++c) {
        const float4* xr = (const float4*)(xp + (size_t)c * NPTS);
        float4 v0 = xr[0], v1 = xr[1];
        const float xv[MPT] = {v0.x,v0.y,v0.z,v0.w, v1.x,v1.y,v1.z,v1.w};
        float qc0 = rdlane(qv0, c), qc1 = rdlane(qv1, c);
        #pragma unroll
        for (int j = 0; j < MPT; ++j) {
            float p0 = qc0 * xv[j];               // fl(q*x)
            acc0[j] = acc0[j] + p0;               // fl(d+p)  (no FMA!)
            float p1 = qc1 * xv[j];
            acc1[j] = acc1[j] + p1;
        }
    }

    float sqm[MPT];
    {
        const float4* sr = (const float4*)(sqb + MPT * t);
        float4 s0 = sr[0], s1 = sr[1];
        sqm[0]=s0.x; sqm[1]=s0.y; sqm[2]=s0.z; sqm[3]=s0.w;
        sqm[4]=s1.x; sqm[5]=s1.y; sqm[6]=s1.z; sqm[7]=s1.w;
    }

#define WAVE_ARGMIN(BD, BI)                                                    \
    _Pragma("unroll")                                                          \
    for (int _off = 32; _off >= 1; _off >>= 1) {                               \
        float _od = __shfl_down(BD, _off);                                     \
        int   _oi = __shfl_down(BI, _off);                                     \
        if (_od < BD || (_od == BD && _oi < BI)) { BD = _od; BI = _oi; }       \
    }

// Tournament top-17: per-wave best in lane-0 regs; per round all threads scan
// the 8 wave-bests; only the winner wave re-reduces; parity double-buffered
// wave-best table -> 1 barrier/round.
#define SELECT(ACC, QI)                                                        \
    {                                                                          \
        const float sqn = sqb[n0 + (QI)];                                      \
        _Pragma("unroll")                                                      \
        for (int j = 0; j < MPT; ++j) {                                        \
            float inner = -2.0f * ACC[j];       /* exact scaling */            \
            float t1    = sqn + inner;                                         \
            ACC[j]      = t1 + sqm[j];          /* fl(fl(sqn+fl(-2d))+sqm) */  \
        }                                                                      \
        unsigned mask = 0;                                                     \
        float cm = 3.0e38f;                                                    \
        int   ci = 0x7fffffff;                                                 \
        _Pragma("unroll")                                                      \
        for (int j = 0; j < MPT; ++j) {                                        \
            float v = ACC[j];                                                  \
            if (v < cm) { cm = v; ci = MPT * t + j; }                          \
        }                                                                      \
        float bd = cm;                                                         \
        int   bi = ci;                                                         \
        WAVE_ARGMIN(bd, bi)                                                    \
        if ((t & 63) == 0) { wbK[QI][0][t >> 6] = bd; wbI[QI][0][t >> 6] = bi; } \
        __syncthreads();                                                       \
        int myOut = 0;                                                         \
        for (int r = 0; r < KSEL; ++r) {                                       \
            const int p = r & 1;                                               \
            float gb = wbK[QI][p][0];                                          \
            int   gi = wbI[QI][p][0];                                          \
            _Pragma("unroll")                                                  \
            for (int w = 1; w < NT / 64; ++w) {                                \
                float od = wbK[QI][p][w];                                      \
                int   oi = wbI[QI][p][w];                                      \
                if (od < gb || (od == gb && oi < gi)) { gb = od; gi = oi; }    \
            }                                                                  \
            if (t < KOUT && r == 2 * t) myOut = gi;  /* capture even ranks */  \
            if (r + 1 < KSEL) {                                                \
                if ((gi >> 9) == (t >> 6)) {         /* winner wave only */    \
                    if ((gi >> 3) == t) {            /* owner: mask+rescan */  \
                        mask |= 1u << (gi & (MPT - 1));                        \
                        cm = 3.0e38f; ci = 0x7fffffff;                         \
                        _Pragma("unroll")                                      \
                        for (int j = 0; j < MPT; ++j) {                        \
                            float v = ACC[j];                                  \
                            if (!((mask >> j) & 1u) && v < cm) { cm = v; ci = MPT * t + j; } \
                        }                                                      \
                    }                                                          \
                    bd = cm; bi = ci;                                          \
                    WAVE_ARGMIN(bd, bi)                                        \
                }                                                              \
                if ((t & 63) == 0) { wbK[QI][p ^ 1][t >> 6] = bd; wbI[QI][p ^ 1][t >> 6] = bi; } \
                __syncthreads();                                               \
            }                                                                  \
        }                                                                      \
        if (t < KOUT) {                                                        \
            int    nq   = n0 + (QI);                                           \
            size_t base = (size_t)((b << 12) + nq) * KOUT;                     \
            out[base + t] = myOut;                                             \
            out[(size_t)BB * NPTS * KOUT + base + t] = nq;                     \
        }                                                                      \
    }

    SELECT(acc0, 0)
    SELECT(acc1, 1)
}

extern "C" void kernel_launch(void* const* d_in, const int* in_sizes, int n_in,
                              void* d_out, int out_size, void* d_ws, size_t ws_size,
                              hipStream_t stream) {
    const float* x   = (const float*)d_in[0];
    float*       sqv = (float*)d_ws;              // 4*4096*4 = 65536 B
    int*         out = (int*)d_out;

    hipLaunchKernelGGL(knn_sq,   dim3((BB * NPTS) / 256), dim3(256), 0, stream, x, sqv);
    hipLaunchKernelGGL(knn_main, dim3((BB * NPTS) / QB),  dim3(NT),  0, stream, x, sqv, out);
}

// Round 11
// 1044.302 us; speedup vs baseline: 3.5260x; 3.5260x over previous
//
#include <hip/hip_runtime.h>

// DenseDilatedKnnGraph: B=4, C=64, N=4096, K=9, DILATION=2 (k_eff=18)
// Input  d_in[0]: float32 (B, C, N, 1)  -> x[b][c][n] at ((b*64)+c)*4096 + n
// Output d_out:   int32   (2, B, N, 9)  -> [0]=neighbor idx (ranks 0,2,..,16), [1]=center n
//
// Grading ref is a numpy fp32 recompute ("ref=np"); we match it BIT-EXACTLY:
//  - einsum dot: sequential c-ascending fp32 accumulate, SEPARATE mul/add
//    roundings (no FMA) -> #pragma clang fp contract(off)
//  - x_square: numpy pairwise-sum AVX512 tree for n=64
//  - key = fl(fl(sq_n + fl(-2*d)) + sq_m); ties -> lower index
//
// Round-11. Laws from r2-r10: occupancy tracks VGPR only; QB=4 needs acc
// small (MPT=16 -> 64 regs is unfixable); s_load/readlane q-delivery both
// lose (lgkmcnt drain / 128-VGPR blowup) -> LDS float4 broadcast is best.
// Config: QB=4, MPT=4, NT=1024. acc=16 regs, 1 dwordx4/thread/c, q via one
// uniform ds_read_b128 per c. 2x arithmetic intensity vs the 543us QB=2
// plateau (x traffic 8.4 -> 4.3 GB).
// Selection (scales to 16 waves, 1 barrier total): per-wave sorted top-17
// via 17 shfl_xor butterfly argmins (4 queries interleaved for ILP) ->
// lists in LDS -> barrier -> waves 0..3 k-way-merge one query each
// (lanes 0..15 = list heads). Same (val,idx)-lex extraction order ->
// bit-exact.

#pragma clang fp contract(off)

#define BB    4
#define CDIM  64
#define NPTS  4096
#define KSEL  17   // need sorted positions 0..16 (every 2nd of top-18)
#define KOUT  9
#define QB    4
#define MPT   4    // m-values per thread
#define NT    1024 // threads per block
#define NW    (NT / 64)  // 16 waves

__global__ __launch_bounds__(256) void knn_sq(const float* __restrict__ x,
                                              float* __restrict__ sq) {
#pragma clang fp contract(off)
    int g = blockIdx.x * 256 + threadIdx.x;       // g = b*NPTS + m
    int b = g >> 12;
    int m = g & (NPTS - 1);
    const float* xb = x + (size_t)b * CDIM * NPTS + m;

    float a[CDIM];
    #pragma unroll
    for (int c = 0; c < CDIM; ++c) {
        float v = xb[c * NPTS];
        a[c] = v * v;
    }
    // numpy pairwise_sum, AVX512 (16-lane) path for n=64:
    float s16[16];
    #pragma unroll
    for (int i = 0; i < 16; ++i)
        s16[i] = (a[i] + a[i + 16]) + (a[i + 32] + a[i + 48]);
    float t8[8];
    #pragma unroll
    for (int i = 0; i < 8; ++i) t8[i] = s16[i] + s16[i + 8];
    float t4[4];
    #pragma unroll
    for (int i = 0; i < 4; ++i) t4[i] = t8[i] + t8[i + 4];
    float u0 = t4[0] + t4[2];
    float u1 = t4[1] + t4[3];
    sq[g] = u0 + u1;
}

__global__ __launch_bounds__(NT) void knn_main(const float* __restrict__ x,
                                               const float* __restrict__ sq,
                                               int* __restrict__ out) {
#pragma clang fp contract(off)
    const int blk  = blockIdx.x;                  // 1024 blocks per b
    const int b    = blk >> 10;
    const int n0   = (blk & 1023) * QB;
    const int t    = threadIdx.x;
    const int lane = t & 63;
    const int wv   = t >> 6;

    __shared__ float4 qT[CDIM];                   // qT[c] = {q0,q1,q2,q3}(c)
    __shared__ float  lK[QB][NW][KSEL];           // per-wave sorted top-17 keys
    __shared__ int    lI[QB][NW][KSEL];           // and indices

    const float* xb  = x + (size_t)b * CDIM * NPTS;
    const float* sqb = sq + (b << 12);
    const float* xp  = xb + MPT * t;              // this thread's m-range

    if (t < CDIM * QB) {                          // 256 threads stage q
        int c = t >> 2, qi = t & 3;
        ((float*)&qT[c])[qi] = xb[(size_t)c * NPTS + n0 + qi];
    }
    __syncthreads();

    // ---- fp32 dots, c ascending, separate mul/add roundings ----
    float acc0[MPT], acc1[MPT], acc2[MPT], acc3[MPT];
    {   // c = 0: init acc = fl(q*x)
        float4 xv = *(const float4*)(xp);
        float4 qq = qT[0];
        const float xvj[4] = {xv.x, xv.y, xv.z, xv.w};
        #pragma unroll
        for (int j = 0; j < 4; ++j) {
            acc0[j] = qq.x * xvj[j];
            acc1[j] = qq.y * xvj[j];
            acc2[j] = qq.z * xvj[j];
            acc3[j] = qq.w * xvj[j];
        }
    }
    #pragma unroll 4
    for (int c = 1; c < CDIM; ++c) {
        float4 xv = *(const float4*)(xp + (size_t)c * NPTS);
        float4 qq = qT[c];                        // uniform -> LDS broadcast
        const float xvj[4] = {xv.x, xv.y, xv.z, xv.w};
        #pragma unroll
        for (int j = 0; j < 4; ++j) {
            float p0 = qq.x * xvj[j];             // fl(q*x)
            acc0[j] = acc0[j] + p0;               // fl(d+p)  (no FMA!)
            float p1 = qq.y * xvj[j];
            acc1[j] = acc1[j] + p1;
            float p2 = qq.z * xvj[j];
            acc2[j] = acc2[j] + p2;
            float p3 = qq.w * xvj[j];
            acc3[j] = acc3[j] + p3;
        }
    }

    // ---- keys: fl(fl(sqn + fl(-2d)) + sqm) ----
    float sqm[4];
    {
        float4 s = *(const float4*)(sqb + MPT * t);
        sqm[0] = s.x; sqm[1] = s.y; sqm[2] = s.z; sqm[3] = s.w;
    }
    const float sqn0 = sqb[n0], sqn1 = sqb[n0 + 1];
    const float sqn2 = sqb[n0 + 2], sqn3 = sqb[n0 + 3];
    #pragma unroll
    for (int j = 0; j < 4; ++j) {
        { float in0 = -2.0f * acc0[j]; float t1 = sqn0 + in0; acc0[j] = t1 + sqm[j]; }
        { float in1 = -2.0f * acc1[j]; float t1 = sqn1 + in1; acc1[j] = t1 + sqm[j]; }
        { float in2 = -2.0f * acc2[j]; float t1 = sqn2 + in2; acc2[j] = t1 + sqm[j]; }
        { float in3 = -2.0f * acc3[j]; float t1 = sqn3 + in3; acc3[j] = t1 + sqm[j]; }
    }

    // ---- per-wave sorted top-17 per query (no barriers; 4 queries ILP) ----
    unsigned msk0 = 0, msk1 = 0, msk2 = 0, msk3 = 0;
    float cm0, cm1, cm2, cm3;
    int   ci0, ci1, ci2, ci3;

#define INIT_CM(CM, CI, ACC)                                                   \
    { CM = 3.0e38f; CI = 0x7fffffff;                                           \
      _Pragma("unroll")                                                        \
      for (int j = 0; j < 4; ++j) {                                            \
          float v = ACC[j];                                                    \
          if (v < CM) { CM = v; CI = MPT * t + j; }                            \
      } }
    INIT_CM(cm0, ci0, acc0)
    INIT_CM(cm1, ci1, acc1)
    INIT_CM(cm2, ci2, acc2)
    INIT_CM(cm3, ci3, acc3)

#define RESCAN(CM, CI, MSK, ACC)                                               \
    { CM = 3.0e38f; CI = 0x7fffffff;                                           \
      _Pragma("unroll")                                                        \
      for (int j = 0; j < 4; ++j) {                                            \
          float v = ACC[j];                                                    \
          if (!((MSK >> j) & 1u) && v < CM) { CM = v; CI = MPT * t + j; }      \
      } }

    for (int r = 0; r < KSEL; ++r) {
        float g0 = cm0, g1 = cm1, g2 = cm2, g3 = cm3;
        int   i0 = ci0, i1 = ci1, i2 = ci2, i3 = ci3;
        #pragma unroll
        for (int s = 1; s <= 32; s <<= 1) {
            float o0 = __shfl_xor(g0, s); int j0 = __shfl_xor(i0, s);
            if (o0 < g0 || (o0 == g0 && j0 < i0)) { g0 = o0; i0 = j0; }
            float o1 = __shfl_xor(g1, s); int j1 = __shfl_xor(i1, s);
            if (o1 < g1 || (o1 == g1 && j1 < i1)) { g1 = o1; i1 = j1; }
            float o2 = __shfl_xor(g2, s); int j2 = __shfl_xor(i2, s);
            if (o2 < g2 || (o2 == g2 && j2 < i2)) { g2 = o2; i2 = j2; }
            float o3 = __shfl_xor(g3, s); int j3 = __shfl_xor(i3, s);
            if (o3 < g3 || (o3 == g3 && j3 < i3)) { g3 = o3; i3 = j3; }
        }
        if (lane == 0) {
            lK[0][wv][r] = g0; lI[0][wv][r] = i0;
            lK[1][wv][r] = g1; lI[1][wv][r] = i1;
            lK[2][wv][r] = g2; lI[2][wv][r] = i2;
            lK[3][wv][r] = g3; lI[3][wv][r] = i3;
        }
        if (i0 == ci0) { msk0 |= 1u << (i0 & 3); RESCAN(cm0, ci0, msk0, acc0) }
        if (i1 == ci1) { msk1 |= 1u << (i1 & 3); RESCAN(cm1, ci1, msk1, acc1) }
        if (i2 == ci2) { msk2 |= 1u << (i2 & 3); RESCAN(cm2, ci2, msk2, acc2) }
        if (i3 == ci3) { msk3 |= 1u << (i3 & 3); RESCAN(cm3, ci3, msk3, acc3) }
    }

    __syncthreads();

    // ---- waves 0..3: 16-way merge of sorted lists for query wv ----
    if (wv < QB) {
        const int q = wv;
        float hk; int hi; int hp = 0;
        if (lane < NW) { hk = lK[q][lane][0]; hi = lI[q][lane][0]; }
        else           { hk = 3.0e38f;        hi = 0x7fffffff;     }
        const int    nq   = n0 + q;
        const size_t base = (size_t)((b << 12) + nq) * KOUT;
        for (int r = 0; r < KSEL; ++r) {
            float gk = hk; int gi = hi;
            #pragma unroll
            for (int s = 1; s <= 8; s <<= 1) {
                float ok = __shfl_xor(gk, s); int oi = __shfl_xor(gi, s);
                if (ok < gk || (ok == gk && oi < gi)) { gk = ok; gi = oi; }
            }
            if ((r & 1) == 0 && lane == 0) out[base + (r >> 1)] = gi;
            if (lane < NW && gi == hi) {              // winner head advances
                ++hp;
                if (hp < KSEL) { hk = lK[q][lane][hp]; hi = lI[q][lane][hp]; }
                else           { hk = 3.0e38f;         hi = 0x7fffffff;      }
            }
        }
        if (lane < KOUT)
            out[(size_t)BB * NPTS * KOUT + base + lane] = nq;
    }
}

extern "C" void kernel_launch(void* const* d_in, const int* in_sizes, int n_in,
                              void* d_out, int out_size, void* d_ws, size_t ws_size,
                              hipStream_t stream) {
    const float* x   = (const float*)d_in[0];
    float*       sqv = (float*)d_ws;              // 4*4096*4 = 65536 B
    int*         out = (int*)d_out;

    hipLaunchKernelGGL(knn_sq,   dim3((BB * NPTS) / 256), dim3(256), 0, stream, x, sqv);
    hipLaunchKernelGGL(knn_main, dim3((BB * NPTS) / QB),  dim3(NT),  0, stream, x, sqv, out);
}

// Round 12
// 560.750 us; speedup vs baseline: 6.5666x; 1.8623x over previous
//
#include <hip/hip_runtime.h>

// DenseDilatedKnnGraph: B=4, C=64, N=4096, K=9, DILATION=2 (k_eff=18)
// Input  d_in[0]: float32 (B, C, N, 1)  -> x[b][c][n] at ((b*64)+c)*4096 + n
// Output d_out:   int32   (2, B, N, 9)  -> [0]=neighbor idx (ranks 0,2,..,16), [1]=center n
//
// Grading ref is a numpy fp32 recompute ("ref=np"); r2 passed absmax 0 with:
//  - einsum dot: sequential c-ascending fp32, SEPARATE mul/add roundings
//  - x_square: numpy pairwise-sum AVX512 tree for n=64
//  - key E = fl(fl(sq_n + fl(-2*d)) + sq_m); ties -> lower index
//
// Round-12: bit-exactness is only needed for keys that can reach the top-17.
// Phase 1 (approx, FMA): A(m) = fmaf(-2, d_fma(m), sq_m) for all m — HALF the
//   FP instructions of the exact mul+add loop. Tournament (r4's, proven) is
//   run only to find T' = 17th-smallest A. |E - sqn - A| <= ~7.5e-4 bound
//   (fp32 dot error at |partials|<~100, x ~ N(0,1)); EPS=0.05 -> 60x margin.
// Candidates = {m : A <= T'+EPS} (superset of exact top-17, ~17-20 expected),
//   gathered via LDS atomics (set is deterministic; order irrelevant).
// Phase 2 (exact): one wave per query recomputes candidates with the verbatim
//   r2 contract (contract(off), c-ascending separate mul/add) and extracts
//   the exact (E,m)-lex order; writes even ranks. Bit-exact output.

#pragma clang fp contract(off)

#define BB    4
#define CDIM  64
#define NPTS  4096
#define KSEL  17   // need sorted positions 0..16 (every 2nd of top-18)
#define KOUT  9
#define QB    2
#define EPS   0.05f
#define CANDMAX 64

__global__ __launch_bounds__(256) void knn_sq(const float* __restrict__ x,
                                              float* __restrict__ sq) {
#pragma clang fp contract(off)
    int g = blockIdx.x * 256 + threadIdx.x;       // g = b*NPTS + m
    int b = g >> 12;
    int m = g & (NPTS - 1);
    const float* xb = x + (size_t)b * CDIM * NPTS + m;

    float a[CDIM];
    #pragma unroll
    for (int c = 0; c < CDIM; ++c) {
        float v = xb[c * NPTS];
        a[c] = v * v;
    }
    // numpy pairwise_sum, AVX512 (16-lane) path for n=64:
    float s16[16];
    #pragma unroll
    for (int i = 0; i < 16; ++i)
        s16[i] = (a[i] + a[i + 16]) + (a[i + 32] + a[i + 48]);
    float t8[8];
    #pragma unroll
    for (int i = 0; i < 8; ++i) t8[i] = s16[i] + s16[i + 8];
    float t4[4];
    #pragma unroll
    for (int i = 0; i < 4; ++i) t4[i] = t8[i] + t8[i + 4];
    float u0 = t4[0] + t4[2];
    float u1 = t4[1] + t4[3];
    sq[g] = u0 + u1;
}

#define FM4Q(ACC, QC, V, J)                                                    \
    ACC[J]     = fmaf(QC, V.x, ACC[J]);                                        \
    ACC[(J)+1] = fmaf(QC, V.y, ACC[(J)+1]);                                    \
    ACC[(J)+2] = fmaf(QC, V.z, ACC[(J)+2]);                                    \
    ACC[(J)+3] = fmaf(QC, V.w, ACC[(J)+3]);

#define WAVE_ARGMIN(BD, BI)                                                    \
    _Pragma("unroll")                                                          \
    for (int _off = 32; _off >= 1; _off >>= 1) {                               \
        float _od = __shfl_down(BD, _off);                                     \
        int   _oi = __shfl_down(BI, _off);                                     \
        if (_od < BD || (_od == BD && _oi < BI)) { BD = _od; BI = _oi; }       \
    }

// Tournament over approx keys; only output is TVAR = 17th-smallest key.
// (r4's proven structure: per-wave best in lane-0 regs, winner-wave-only
// re-reduce, parity double-buffered table, 1 barrier/round.)
#define SELECT_T(ACC, QI, TVAR)                                                \
    {                                                                          \
        unsigned mask = 0;                                                     \
        float cm = 3.0e38f;                                                    \
        int   ci = 0x7fffffff;                                                 \
        _Pragma("unroll")                                                      \
        for (int j = 0; j < 16; ++j) {                                         \
            float v = ACC[j];                                                  \
            if (v < cm) { cm = v; ci = 16 * t + j; }                           \
        }                                                                      \
        float bd = cm;                                                         \
        int   bi = ci;                                                         \
        WAVE_ARGMIN(bd, bi)                                                    \
        if ((t & 63) == 0) { wbK[QI][0][t >> 6] = bd; wbI[QI][0][t >> 6] = bi; } \
        __syncthreads();                                                       \
        for (int r = 0; r < KSEL; ++r) {                                       \
            const int p = r & 1;                                               \
            float gb = wbK[QI][p][0];                                          \
            int   gi = wbI[QI][p][0];                                          \
            _Pragma("unroll")                                                  \
            for (int w = 1; w < 4; ++w) {                                      \
                float od = wbK[QI][p][w];                                      \
                int   oi = wbI[QI][p][w];                                      \
                if (od < gb || (od == gb && oi < gi)) { gb = od; gi = oi; }    \
            }                                                                  \
            TVAR = gb;                                                         \
            if (r + 1 < KSEL) {                                                \
                if ((gi >> 10) == (t >> 6)) {        /* winner wave only */    \
                    if ((gi >> 4) == t) {            /* owner: mask+rescan */  \
                        mask |= 1u << (gi & 15);                               \
                        cm = 3.0e38f; ci = 0x7fffffff;                         \
                        _Pragma("unroll")                                      \
                        for (int j = 0; j < 16; ++j) {                         \
                            float v = ACC[j];                                  \
                            if (!((mask >> j) & 1u) && v < cm) { cm = v; ci = 16 * t + j; } \
                        }                                                      \
                    }                                                          \
                    bd = cm; bi = ci;                                          \
                    WAVE_ARGMIN(bd, bi)                                        \
                }                                                              \
                if ((t & 63) == 0) { wbK[QI][p ^ 1][t >> 6] = bd; wbI[QI][p ^ 1][t >> 6] = bi; } \
                __syncthreads();                                               \
            }                                                                  \
        }                                                                      \
    }

__global__ __launch_bounds__(256) void knn_main(const float* __restrict__ x,
                                                const float* __restrict__ sq,
                                                int* __restrict__ out) {
#pragma clang fp contract(off)
    const int blk = blockIdx.x;                   // 2048 blocks per b
    const int b   = blk >> 11;
    const int n0  = (blk & 2047) * QB;
    const int t   = threadIdx.x;

    __shared__ float2 qs2[CDIM];                  // {q0(c), q1(c)}
    __shared__ float  wbK[QB][2][4];
    __shared__ int    wbI[QB][2][4];
    __shared__ int    candCnt[QB];
    __shared__ int    candM[QB][CANDMAX];

    const float* xb  = x + (size_t)b * CDIM * NPTS;
    const float* sqb = sq + (b << 12);
    const float* xp  = xb + 16 * t;               // this thread's m-range

    if (t < CDIM)
        qs2[t] = make_float2(xb[(size_t)t * NPTS + n0],
                             xb[(size_t)t * NPTS + n0 + 1]);
    if (t < QB) candCnt[t] = 0;
    __syncthreads();

    // ---- Phase 1: approx dots via FMA (half the instructions) ----
    float acc0[16], acc1[16];
    #pragma unroll
    for (int j = 0; j < 16; ++j) { acc0[j] = 0.0f; acc1[j] = 0.0f; }

    #pragma unroll 2
    for (int c = 0; c < CDIM; ++c) {
        const float4* xr = (const float4*)(xp + (size_t)c * NPTS);
        float4 v0 = xr[0], v1 = xr[1], v2 = xr[2], v3 = xr[3];
        float2 qc = qs2[c];
        FM4Q(acc0, qc.x, v0, 0)  FM4Q(acc0, qc.x, v1, 4)
        FM4Q(acc0, qc.x, v2, 8)  FM4Q(acc0, qc.x, v3, 12)
        FM4Q(acc1, qc.y, v0, 0)  FM4Q(acc1, qc.y, v1, 4)
        FM4Q(acc1, qc.y, v2, 8)  FM4Q(acc1, qc.y, v3, 12)
    }

    // approx key A = fmaf(-2, d, sq_m)   (sq_n constant dropped: order-free)
    {
        const float4* sr = (const float4*)(sqb + 16 * t);
        float4 s0 = sr[0], s1 = sr[1], s2 = sr[2], s3 = sr[3];
        const float sm[16] = {s0.x,s0.y,s0.z,s0.w, s1.x,s1.y,s1.z,s1.w,
                              s2.x,s2.y,s2.z,s2.w, s3.x,s3.y,s3.z,s3.w};
        #pragma unroll
        for (int j = 0; j < 16; ++j) {
            acc0[j] = fmaf(-2.0f, acc0[j], sm[j]);
            acc1[j] = fmaf(-2.0f, acc1[j], sm[j]);
        }
    }

    // ---- thresholds (17th-smallest approx key per query) ----
    float T0 = 0.0f, T1 = 0.0f;
    SELECT_T(acc0, 0, T0)
    SELECT_T(acc1, 1, T1)

    // ---- candidate gather: provable superset of exact top-17 ----
    #pragma unroll
    for (int j = 0; j < 16; ++j) {
        if (acc0[j] <= T0 + EPS) {
            int p = atomicAdd(&candCnt[0], 1);
            if (p < CANDMAX) candM[0][p] = 16 * t + j;
        }
        if (acc1[j] <= T1 + EPS) {
            int p = atomicAdd(&candCnt[1], 1);
            if (p < CANDMAX) candM[1][p] = 16 * t + j;
        }
    }
    __syncthreads();

    // ---- Phase 2: exact recompute + exact extraction (1 wave/query) ----
    const int wv = t >> 6, lane = t & 63;
    if (wv < QB) {
        const int qi  = wv;
        const int cnt = min(candCnt[qi], CANDMAX);
        const int nq  = n0 + qi;
        float E   = 3.0e38f;
        int   myM = 0x7fffffff;
        if (lane < cnt) {
            myM = candM[qi][lane];
            const float* xm = xb + myM;
            // exact contract: c-ascending, separate mul/add roundings
            float d = (qi == 0 ? qs2[0].x : qs2[0].y) * xm[0];
            for (int c = 1; c < CDIM; ++c) {
                float qc = (qi == 0) ? qs2[c].x : qs2[c].y;
                float p  = qc * xm[(size_t)c * NPTS];
                d = d + p;                        // no FMA (contract off)
            }
            float inner = -2.0f * d;              // exact scaling
            float t1    = sqb[nq] + inner;
            E = t1 + sqb[myM];                    // fl(fl(sqn+fl(-2d))+sqm)
        }
        const size_t base = (size_t)((b << 12) + nq) * KOUT;
        for (int r = 0; r < KSEL; ++r) {
            float gk = E; int gi = myM;
            #pragma unroll
            for (int s = 32; s >= 1; s >>= 1) {
                float ok = __shfl_down(gk, s);
                int   oi = __shfl_down(gi, s);
                if (ok < gk || (ok == gk && oi < gi)) { gk = ok; gi = oi; }
            }
            gk = __shfl(gk, 0); gi = __shfl(gi, 0);   // broadcast winner
            if ((r & 1) == 0 && lane == 0) out[base + (r >> 1)] = gi;
            if (myM == gi) E = 3.0e38f;               // remove winner
        }
        if (lane < KOUT)
            out[(size_t)BB * NPTS * KOUT + base + lane] = nq;
    }
}

extern "C" void kernel_launch(void* const* d_in, const int* in_sizes, int n_in,
                              void* d_out, int out_size, void* d_ws, size_t ws_size,
                              hipStream_t stream) {
    const float* x   = (const float*)d_in[0];
    float*       sqv = (float*)d_ws;              // 4*4096*4 = 65536 B
    int*         out = (int*)d_out;

    hipLaunchKernelGGL(knn_sq,   dim3((BB * NPTS) / 256), dim3(256), 0, stream, x, sqv);
    hipLaunchKernelGGL(knn_main, dim3((BB * NPTS) / QB),  dim3(256), 0, stream, x, sqv, out);
}